// Round 1
// baseline (9892.091 us; speedup 1.0000x reference)
//
#include <hip/hip_runtime.h>
#include <math.h>

#define TT 256
#define BB 256
#define ID 512
#define HD 512
#define G4 2048            // 4*H
#define KT 1024            // IN + H
#define TBH ((size_t)TT * BB * HD)

// ---------------------------------------------------------------------------
// Prep: WcT[k][j] = k<512 ? W_ih[j][k] : W_hh[j][k-512]   (k-major, coalesced
// per-k reads in the step kernel), bc[j] = b_ih[j] + b_hh[j].
// ---------------------------------------------------------------------------
__global__ void prep_kernel(const float* __restrict__ W_ih,
                            const float* __restrict__ W_hh,
                            const float* __restrict__ b_ih,
                            const float* __restrict__ b_hh,
                            float* __restrict__ WcT,
                            float* __restrict__ bc) {
    int idx = blockIdx.x * 256 + threadIdx.x;   // over KT*G4 = 2M elements
    int k = idx >> 11;          // / 2048
    int j = idx & (G4 - 1);
    float v = (k < ID) ? W_ih[(size_t)j * ID + k]
                       : W_hh[(size_t)j * HD + (k - ID)];
    WcT[idx] = v;
    if (idx < G4) bc[idx] = b_ih[idx] + b_hh[idx];
}

// ---------------------------------------------------------------------------
// One LSTM time step. Grid: (16 hcol-tiles of 32, 16 batch-tiles of 16).
// 512 threads. h/c state is read from / written to d_out (hxs at t-1, cxs at
// t-1), so no scratch state is needed and every call recomputes from t=0.
// ---------------------------------------------------------------------------
__launch_bounds__(512, 2)
__global__ void lstm_step(int t, int use_ws,
                          const float* __restrict__ feat,
                          const int*  __restrict__ mask,
                          const float* __restrict__ W_ih,
                          const float* __restrict__ W_hh,
                          const float* __restrict__ b_ih,
                          const float* __restrict__ b_hh,
                          const float* __restrict__ WcT,
                          const float* __restrict__ bc,
                          float* __restrict__ out) {
    __shared__ float4 xh4[16][256];   // [batch][k/4] : 16 x 1024 floats = 64KB
    const int tid = threadIdx.x;
    const int c0 = blockIdx.x * 32;   // h-column tile base
    const int b0 = blockIdx.y * 16;   // batch tile base

    float* hxs0 = out;
    float* hxs1 = out + TBH;
    float* cxs  = out + 2 * TBH;

    // ---- phase 1: stage [x_t | keep * h_{t-1}] into LDS ----
    for (int e = tid; e < 16 * 256; e += 512) {
        int bl = e >> 8;          // local batch
        int q  = e & 255;         // float4 index within 1024-float row
        int b  = b0 + bl;
        float4 v;
        if (q < 128) {
            v = reinterpret_cast<const float4*>(feat + ((size_t)t * BB + b) * ID)[q];
        } else if (t == 0) {
            v = make_float4(0.f, 0.f, 0.f, 0.f);
        } else {
            float keep = 1.0f - (float)mask[t * BB + b];
            v = reinterpret_cast<const float4*>(hxs0 + ((size_t)(t - 1) * BB + b) * HD)[q - 128];
            v.x *= keep; v.y *= keep; v.z *= keep; v.w *= keep;
        }
        xh4[bl][q] = v;
    }
    __syncthreads();

    // ---- phase 2: gate dot products ----
    // thread: one gate column (lc in [0,128): gate = lc>>5, hcol = lc&31),
    // 4 batches (bh = tid>>7 in [0,4)).
    const int lc = tid & 127;
    const int bh = tid >> 7;
    const int j  = (lc >> 5) * HD + c0 + (lc & 31);   // global gate row
    float acc[4] = {0.f, 0.f, 0.f, 0.f};

    if (use_ws) {
        for (int k = 0; k < KT; k += 4) {
            float w0 = WcT[(size_t)(k + 0) * G4 + j];
            float w1 = WcT[(size_t)(k + 1) * G4 + j];
            float w2 = WcT[(size_t)(k + 2) * G4 + j];
            float w3 = WcT[(size_t)(k + 3) * G4 + j];
            #pragma unroll
            for (int i = 0; i < 4; ++i) {
                float4 x = xh4[bh * 4 + i][k >> 2];
                acc[i] = fmaf(x.x, w0, acc[i]);
                acc[i] = fmaf(x.y, w1, acc[i]);
                acc[i] = fmaf(x.z, w2, acc[i]);
                acc[i] = fmaf(x.w, w3, acc[i]);
            }
        }
    } else {
        // fallback if ws too small: direct row-major weight reads
        const float4* wi = reinterpret_cast<const float4*>(W_ih + (size_t)j * ID);
        const float4* wh = reinterpret_cast<const float4*>(W_hh + (size_t)j * HD);
        for (int k = 0; k < KT; k += 4) {
            float4 w = (k < ID) ? wi[k >> 2] : wh[(k - ID) >> 2];
            #pragma unroll
            for (int i = 0; i < 4; ++i) {
                float4 x = xh4[bh * 4 + i][k >> 2];
                acc[i] = fmaf(x.x, w.x, acc[i]);
                acc[i] = fmaf(x.y, w.y, acc[i]);
                acc[i] = fmaf(x.z, w.z, acc[i]);
                acc[i] = fmaf(x.w, w.w, acc[i]);
            }
        }
    }
    float gbias = use_ws ? bc[j] : (b_ih[j] + b_hh[j]);
    __syncthreads();

    // ---- phase 3: exchange gates via LDS (reuse xh4 memory) ----
    float* gbuf = reinterpret_cast<float*>(xh4);   // [128 gate-col][16 batch]
    #pragma unroll
    for (int i = 0; i < 4; ++i) gbuf[lc * 16 + bh * 4 + i] = acc[i] + gbias;
    __syncthreads();

    // ---- phase 4: pointwise LSTM cell update + output writes ----
    {
        int hc = tid & 31;        // local h column
        int bl = tid >> 5;        // local batch
        int b  = b0 + bl;
        float keep = 1.0f - (float)mask[t * BB + b];
        float cp = 0.f;
        if (t > 0)
            cp = cxs[((size_t)(t - 1) * BB + b) * HD + c0 + hc];
        cp *= keep;

        float ig = gbuf[(0 * 32 + hc) * 16 + bl];
        float fg = gbuf[(1 * 32 + hc) * 16 + bl];
        float gg = gbuf[(2 * 32 + hc) * 16 + bl];
        float og = gbuf[(3 * 32 + hc) * 16 + bl];
        ig = 1.0f / (1.0f + __expf(-ig));
        fg = 1.0f / (1.0f + __expf(-fg));
        gg = tanhf(gg);
        og = 1.0f / (1.0f + __expf(-og));
        float cn = fg * cp + ig * gg;
        float hn = og * tanhf(cn);

        size_t o = ((size_t)t * BB + b) * HD + c0 + hc;
        hxs0[o] = hn;
        hxs1[o] = hn;
        cxs[o]  = cn;
    }
}

extern "C" void kernel_launch(void* const* d_in, const int* in_sizes, int n_in,
                              void* d_out, int out_size, void* d_ws, size_t ws_size,
                              hipStream_t stream) {
    const float* feat = (const float*)d_in[0];
    const int*   mask = (const int*)d_in[1];
    const float* W_ih = (const float*)d_in[2];
    const float* W_hh = (const float*)d_in[3];
    const float* b_ih = (const float*)d_in[4];
    const float* b_hh = (const float*)d_in[5];
    float* out = (float*)d_out;

    float* WcT = (float*)d_ws;
    float* bc  = WcT + (size_t)KT * G4;
    const size_t ws_needed = ((size_t)KT * G4 + G4) * sizeof(float);
    int use_ws = (d_ws != nullptr && ws_size >= ws_needed) ? 1 : 0;

    if (use_ws) {
        prep_kernel<<<(KT * G4) / 256, 256, 0, stream>>>(W_ih, W_hh, b_ih, b_hh, WcT, bc);
    }

    dim3 grid(16, 16);   // 16 hcol-tiles x 16 batch-tiles
    for (int t = 0; t < TT; ++t) {
        lstm_step<<<grid, 512, 0, stream>>>(t, use_ws, feat, mask,
                                            W_ih, W_hh, b_ih, b_hh, WcT, bc, out);
    }
}